// Round 1
// baseline (403.778 us; speedup 1.0000x reference)
//
#include <hip/hip_runtime.h>
#include <cstdint>
#include <cstddef>

#define Bn 128
#define Tn 1024
#define Vn 256
#define Ln 128
#define Sn 257            // 2L+1
#define BLANKC 255
#define NEGF (-1e30f)
#define LPSTRIDE 132      // 129 used, padded
#define MID 512           // meet-in-the-middle time index

__device__ __forceinline__ float lse3f(float a, float b, float c) {
    float m = fmaxf(a, fmaxf(b, c));
    float ms = (m <= NEGF) ? 0.f : m;
    float s = __expf(a - ms) + __expf(b - ms) + __expf(c - ms);
    float r = __logf(s) + ms;
    return (m <= NEGF) ? NEGF : r;
}

// ---------------- Kernel A: per-(b,t) log-softmax + gather to compact fp16 emissions
__global__ __launch_bounds__(256) void ctc_lse_gather(
    const float* __restrict__ logits, const int* __restrict__ labels,
    _Float16* __restrict__ lp) {
    int t = blockIdx.x, b = blockIdx.y, tid = threadIdx.x;
    __shared__ float row[Vn];
    __shared__ float red[8];
    size_t base = ((size_t)b * Tn + t) * Vn;
    float x = logits[base + tid];
    row[tid] = x;
    float mx = x;
#pragma unroll
    for (int o = 32; o; o >>= 1) mx = fmaxf(mx, __shfl_xor(mx, o, 64));
    int w = tid >> 6, lane = tid & 63;
    if (lane == 0) red[w] = mx;
    __syncthreads();
    mx = fmaxf(fmaxf(red[0], red[1]), fmaxf(red[2], red[3]));
    float e = __expf(x - mx);
    float sm = e;
#pragma unroll
    for (int o = 32; o; o >>= 1) sm += __shfl_xor(sm, o, 64);
    if (lane == 0) red[4 + w] = sm;
    __syncthreads();
    float lse = mx + __logf(red[4] + red[5] + red[6] + red[7]);
    if (tid < Ln + 1) {
        int lab = (tid < Ln) ? labels[b * Ln + tid] : BLANKC;
        lp[((size_t)b * Tn + t) * LPSTRIDE + tid] = (_Float16)(row[lab] - lse);
    }
}

// ---------------- Kernel B: bidirectional half-scans. blockIdx: 2*b + dir (0=fwd,1=bwd)
__global__ __launch_bounds__(320) void ctc_scan(
    const _Float16* __restrict__ lp, const int* __restrict__ labels,
    float* __restrict__ mid) {
    int b = blockIdx.x >> 1, dir = blockIdx.x & 1, tid = threadIdx.x;
    __shared__ float buf[2][Sn + 4];   // [0..1]=NEG sentinels, data at +2, [Sn+2..Sn+3]=NEG
    bool active = tid < Sn;
    int s = active ? tid : 0;
    bool odd = (s & 1) != 0;
    int j = (s - 1) >> 1;              // label index when odd
    int col = odd ? j : Ln;            // Ln==128 is the blank slot
    const int* y = labels + b * Ln;
    bool skipFwd = odd && (j > 0) && (y[j] != y[j - 1]);
    bool skipBwd = odd && (s + 2 <= Sn - 1) && (y[j + 1] != y[j]);
    const _Float16* lpB = lp + (size_t)b * Tn * LPSTRIDE + col;

    if (tid < 2) {
        buf[0][tid] = NEGF; buf[1][tid] = NEGF;
        buf[0][Sn + 2 + tid] = NEGF; buf[1][Sn + 2 + tid] = NEGF;
    }

    float a;
    int nsteps;
    if (dir == 0) {                      // forward: alpha_0 init, steps t=1..MID
        a = (s <= 1) ? (float)lpB[0] : NEGF;
        nsteps = MID;
    } else {                             // backward: beta-hat_{T-1} init, steps use lp at t+1 = T-1..MID+1
        a = (s >= Sn - 2) ? 0.f : NEGF;
        nsteps = Tn - 1 - MID;           // 511
    }

    auto toff = [&](int i) -> size_t {
        i = (i < nsteps) ? i : (nsteps - 1);
        int t = (dir == 0) ? (1 + i) : (Tn - 1 - i);
        return (size_t)t * LPSTRIDE;
    };

    float curv[8], nxtv[8];
#pragma unroll
    for (int k = 0; k < 8; ++k) curv[k] = (float)lpB[toff(k)];
    int cur = 0;
    for (int i0 = 0; i0 < nsteps; i0 += 8) {
#pragma unroll
        for (int k = 0; k < 8; ++k) nxtv[k] = (float)lpB[toff(i0 + 8 + k)];
        if (dir == 0) {
#pragma unroll
            for (int k = 0; k < 8; ++k) {
                if (i0 + k >= nsteps) break;          // uniform across block
                if (active) buf[cur][2 + s] = a;      // alpha_{t-1}
                __syncthreads();
                float a2 = buf[cur][2 + s - 1];
                float a3 = skipFwd ? buf[cur][2 + s - 2] : NEGF;
                a = lse3f(a, a2, a3) + curv[k];
                cur ^= 1;
            }
        } else {
#pragma unroll
            for (int k = 0; k < 8; ++k) {
                if (i0 + k >= nsteps) break;
                float h = a + curv[k];                // beta-hat_{t+1}[s] + lp_{t+1}[s]
                if (active) buf[cur][2 + s] = h;
                __syncthreads();
                float h1 = buf[cur][2 + s + 1];
                float h2 = skipBwd ? buf[cur][2 + s + 2] : NEGF;
                a = lse3f(h, h1, h2);
                cur ^= 1;
            }
        }
#pragma unroll
        for (int k = 0; k < 8; ++k) curv[k] = nxtv[k];
    }
    if (active) mid[((size_t)b * 2 + dir) * Sn + s] = a;
}

// ---------------- Kernel C: combine at the meet point, mean-reduce into out
__global__ __launch_bounds__(320) void ctc_final(
    const float* __restrict__ mid, float* __restrict__ out) {
    int b = blockIdx.x, tid = threadIdx.x;
    __shared__ float red[10];
    bool active = tid < Sn;
    float v = active ? (mid[((size_t)b * 2) * Sn + tid] + mid[((size_t)b * 2 + 1) * Sn + tid])
                     : NEGF;
    float mx = v;
#pragma unroll
    for (int o = 32; o; o >>= 1) mx = fmaxf(mx, __shfl_xor(mx, o, 64));
    int w = tid >> 6, lane = tid & 63;
    if (lane == 0) red[w] = mx;
    __syncthreads();
    mx = fmaxf(fmaxf(fmaxf(red[0], red[1]), fmaxf(red[2], red[3])), red[4]);
    float e = active ? __expf(v - mx) : 0.f;
    float sm = e;
#pragma unroll
    for (int o = 32; o; o >>= 1) sm += __shfl_xor(sm, o, 64);
    if (lane == 0) red[5 + w] = sm;
    __syncthreads();
    if (tid == 0) {
        float tot = red[5] + red[6] + red[7] + red[8] + red[9];
        float ll = mx + __logf(tot);
        atomicAdd(out, -ll * (1.0f / Bn));
    }
}

// ---------------- Fallback (ws too small): fully fused, one block per batch
__global__ __launch_bounds__(320) void ctc_fused(
    const float* __restrict__ logits, const int* __restrict__ labels,
    float* __restrict__ out) {
    int b = blockIdx.x, tid = threadIdx.x;
    __shared__ float row[Vn];
    __shared__ float red[12];
    __shared__ float buf[2][Sn + 4];
    bool active = tid < Sn;
    int s = active ? tid : 0;
    bool odd = (s & 1) != 0;
    int j = (s - 1) >> 1;
    const int* y = labels + b * Ln;
    int ext = odd ? y[j] : BLANKC;
    bool skipF = odd && (j > 0) && (y[j] != y[j - 1]);
    if (tid < 2) {
        buf[0][tid] = NEGF; buf[1][tid] = NEGF;
        buf[0][Sn + 2 + tid] = NEGF; buf[1][Sn + 2 + tid] = NEGF;
    }
    const float* lg = logits + (size_t)b * Tn * Vn;
    float a = NEGF;
    int cur = 0;
    int w = tid >> 6, lane = tid & 63;
    for (int t = 0; t < Tn; ++t) {
        float x = (tid < Vn) ? lg[(size_t)t * Vn + tid] : -3.0e38f;
        if (tid < Vn) row[tid] = x;
        float mx = x;
#pragma unroll
        for (int o = 32; o; o >>= 1) mx = fmaxf(mx, __shfl_xor(mx, o, 64));
        if (lane == 0) red[w] = mx;
        __syncthreads();
        mx = fmaxf(fmaxf(fmaxf(red[0], red[1]), fmaxf(red[2], red[3])), red[4]);
        float e = (tid < Vn) ? __expf(x - mx) : 0.f;
        float sm = e;
#pragma unroll
        for (int o = 32; o; o >>= 1) sm += __shfl_xor(sm, o, 64);
        if (lane == 0) red[5 + w] = sm;
        __syncthreads();
        float lse = mx + __logf(red[5] + red[6] + red[7] + red[8] + red[9]);
        float lpv = row[ext] - lse;
        if (t == 0) {
            a = (s <= 1) ? lpv : NEGF;
        } else {
            if (active) buf[cur][2 + s] = a;
            __syncthreads();
            float a2 = buf[cur][2 + s - 1];
            float a3 = skipF ? buf[cur][2 + s - 2] : NEGF;
            a = lse3f(a, a2, a3) + lpv;
            cur ^= 1;
        }
        __syncthreads();
    }
    if (s == Sn - 1) red[10] = a;
    if (s == Sn - 2) red[11] = a;
    __syncthreads();
    if (tid == 0) {
        float m = fmaxf(red[10], red[11]);
        float ll = m + __logf(__expf(red[10] - m) + __expf(red[11] - m));
        atomicAdd(out, -ll * (1.0f / Bn));
    }
}

extern "C" void kernel_launch(void* const* d_in, const int* in_sizes, int n_in,
                              void* d_out, int out_size, void* d_ws, size_t ws_size,
                              hipStream_t stream) {
    const int*   y_true = (const int*)d_in[0];
    const float* y_pred = (const float*)d_in[1];
    float* out = (float*)d_out;

    hipMemsetAsync(out, 0, sizeof(float), stream);

    size_t midBytes = (size_t)Bn * 2 * Sn * sizeof(float);       // 263168 B
    size_t lpBytes  = (size_t)Bn * Tn * LPSTRIDE * sizeof(_Float16); // ~34.6 MB
    if (ws_size >= midBytes + lpBytes) {
        float*     mid = (float*)d_ws;
        _Float16*  lp  = (_Float16*)((char*)d_ws + midBytes);
        ctc_lse_gather<<<dim3(Tn, Bn), 256, 0, stream>>>(y_pred, y_true, lp);
        ctc_scan<<<dim3(Bn * 2), 320, 0, stream>>>(lp, y_true, mid);
        ctc_final<<<dim3(Bn), 320, 0, stream>>>(mid, out);
    } else {
        ctc_fused<<<dim3(Bn), 320, 0, stream>>>(y_pred, y_true, out);
    }
}

// Round 4
// 250.408 us; speedup vs baseline: 1.6125x; 1.6125x over previous
//
#include <hip/hip_runtime.h>
#include <cstdint>
#include <cstddef>

#define Bn 128
#define Tn 1024
#define Vn 256
#define Ln 128
#define Sn 257            // 2L+1
#define BLANKC 255
#define NEGF (-1e30f)
#define MS 260            // mid row stride in floats (260*4=1040, 16B-aligned rows)
#define LN2D 0.6931471805599453
#define RTARGET 300       // post-rescale band max ~2^300; 64-step decay ~2^-475 -> dip ~2^-175

typedef _Float16 h2 __attribute__((ext_vector_type(2)));

__device__ __forceinline__ float lse3f(float a, float b, float c) {
    float m = fmaxf(a, fmaxf(b, c));
    float ms = (m <= NEGF) ? 0.f : m;
    float s = __expf(a - ms) + __expf(b - ms) + __expf(c - ms);
    float r = __logf(s) + ms;
    return (m <= NEGF) ? NEGF : r;
}

// ---------------- Kernel A: softmax probs gathered at label cols (fp16) ------
// plab[b][t][j] = p_t(y[j]) (128 fp16/row), pblank[b][t] = p_t(blank).
// One wave per t-row, float4 loads, wave-synchronous LDS gather.
__global__ __launch_bounds__(256) void ctc_prep(
    const float* __restrict__ logits, const int* __restrict__ labels,
    _Float16* __restrict__ plab, _Float16* __restrict__ pblank) {
    int w = threadIdx.x >> 6, lane = threadIdx.x & 63;
    int b = blockIdx.y;
    int t0 = (blockIdx.x * 4 + w) * 16;
    __shared__ float eb[4][256];
    int2 yy = *(const int2*)(labels + b * Ln + 2 * lane);   // y[2l], y[2l+1]
    const float* rp = logits + ((size_t)(b * Tn + t0)) * Vn + 4 * lane;
    size_t prow = (size_t)(b * Tn + t0) * Ln + 2 * lane;
    int pbi = b * Tn + t0;
#pragma unroll 2
    for (int r = 0; r < 16; ++r) {
        float4 x = *(const float4*)rp;
        float e0 = __expf(x.x), e1 = __expf(x.y), e2 = __expf(x.z), e3 = __expf(x.w);
        float ssum = (e0 + e1) + (e2 + e3);
#pragma unroll
        for (int o = 1; o < 64; o <<= 1) ssum += __shfl_xor(ssum, o, 64);
        *(float4*)&eb[w][4 * lane] = make_float4(e0, e1, e2, e3);
        __builtin_amdgcn_wave_barrier();        // same-wave LDS: block compiler reorder
        float inv = __builtin_amdgcn_rcpf(ssum);
        float pl0 = eb[w][yy.x] * inv;
        float pl1 = eb[w][yy.y] * inv;
        float pb  = eb[w][255]  * inv;
        __builtin_amdgcn_wave_barrier();
        h2 hp; hp.x = (_Float16)pl0; hp.y = (_Float16)pl1;
        *(h2*)(plab + prow) = hp;
        if (lane == 0) pblank[pbi] = (_Float16)pb;
        rp += Vn; prow += Ln; ++pbi;
    }
}

// ---------------- Kernel B: f64 linear-space bidirectional half-scans --------
// One wave per chain; lane l owns states 4l..4l+3 (+ dup of 4l+4; lane63's a4
// is state 256). f64 states: gradual underflow (f64 denormals are IEEE on
// AMDGPU) gives >=625-nat live window below band max with a wave-uniform
// power-of-2 rescale every 64 steps. No floor => no spurious mass.
template<int DIR, int NS>
__device__ __forceinline__ void scan_core(
    const _Float16* __restrict__ plB, const _Float16* __restrict__ pbB,
    double sk1, double sk3, double sB1, double sB3,
    double i0, double i1, int lane, float* __restrict__ row) {
    double a0 = 0., a1 = 0., a2 = 0., a3 = 0., a4 = 0.;
    if (DIR == 0) { if (lane == 0) { a0 = i0; a1 = i1; } }
    else          { if (lane == 63) { a3 = 1.; a4 = 1.; } }
    unsigned lvA[16], lvB[16]; unsigned short bvA[16], bvB[16];
    auto tof = [&](int i) { if (i >= NS) i = NS - 1; return DIR ? (Tn - 1 - i) : (1 + i); };
    auto loadP = [&](int per, unsigned* lv, unsigned short* bv) {
#pragma unroll
        for (int k = 0; k < 16; ++k) {
            int t = tof(per * 16 + k);
            lv[k] = *(const unsigned*)(plB + (size_t)t * Ln);
            bv[k] = *(const unsigned short*)(pbB + t);
        }
    };
    int sumD = 0;
    auto doP = [&](int per, const unsigned* lv, const unsigned short* bv) {
#pragma unroll
        for (int k = 0; k < 16; ++k) {
            int i = per * 16 + k;
            if (NS < 512 && i >= NS) break;   // uniform; folded away for NS=512
            h2 hv = __builtin_bit_cast(h2, lv[k]);
            double pl0 = (double)(float)hv.x, pl1 = (double)(float)hv.y;
            double pb  = (double)(float)__builtin_bit_cast(_Float16, bv[k]);
            if (DIR == 0) {
                double pv = __shfl_up(a3, 1, 64);
                if (lane == 0) pv = 0.;                      // s=0 boundary
                double n0 = (a0 + pv) * pb;                  // even: no skip
                double n1 = (a1 + a0 + sk1 * pv) * pl0;      // s=4l+1, skip from prev.s3
                double n2 = (a2 + a1) * pb;
                double n3 = (a3 + a2 + sk3 * a1) * pl1;      // s=4l+3, skip local
                double n4 = (a4 + a3) * pb;                  // dup of next lane's a0
                a0 = n0; a1 = n1; a2 = n2; a3 = n3; a4 = n4;
            } else {
                double h0v = a0 * pb, h1v = a1 * pl0, h2v = a2 * pb, h3v = a3 * pl1, h4v = a4 * pb;
                double nh0 = __shfl_down(h0v, 1, 64);
                double nh1 = __shfl_down(h1v, 1, 64);
                double t1 = (lane == 63) ? h4v : nh0;        // s+1 of state 4l+3
                a3 = h3v + t1 + sB3 * nh1;                   // sB3=0 on lane63
                a2 = h2v + h3v;
                a1 = h1v + h2v + sB1 * h3v;
                a0 = h0v + h1v;
                a4 = h4v;                                    // s=256: no successors
            }
        }
    };
    auto rescale = [&]() {
        double rm = fmax(fmax(fmax(a0, a1), fmax(a2, a3)), a4);
#pragma unroll
        for (int o = 1; o < 64; o <<= 1) rm = fmax(rm, __shfl_xor(rm, o, 64));
        if (rm > 0.) {
            long long bits = __double_as_longlong(rm);
            int E = (int)((bits >> 52) & 0x7ff) - 1023;      // subnormal => -1023, fine
            int D = RTARGET - E;
            D = (D > 1000) ? 1000 : ((D < -1000) ? -1000 : D);
            double sc = __longlong_as_double((long long)(D + 1023) << 52);  // exact 2^D
            a0 *= sc; a1 *= sc; a2 *= sc; a3 *= sc; a4 *= sc;
            sumD += D;
        }
    };
    loadP(0, lvA, bvA);
    for (int pp = 0; pp < 16; ++pp) {       // 2 periods (32 steps) per iteration
        loadP(2 * pp + 1, lvB, bvB);
        doP(2 * pp, lvA, bvA);
        if (pp < 15) loadP(2 * pp + 2, lvA, bvA);
        doP(2 * pp + 1, lvB, bvB);
        if ((pp & 1) == 1) rescale();        // every 64 steps
    }
    double ls = (double)sumD * LN2D;         // stored = true * 2^sumD
    float o0 = a0 > 0. ? (float)(log(a0) - ls) : NEGF;
    float o1 = a1 > 0. ? (float)(log(a1) - ls) : NEGF;
    float o2 = a2 > 0. ? (float)(log(a2) - ls) : NEGF;
    float o3 = a3 > 0. ? (float)(log(a3) - ls) : NEGF;
    *(float4*)(row + 4 * lane) = make_float4(o0, o1, o2, o3);
    if (lane == 63) row[256] = a4 > 0. ? (float)(log(a4) - ls) : NEGF;
}

__global__ __launch_bounds__(64) void ctc_scan2(
    const _Float16* __restrict__ plab, const _Float16* __restrict__ pblank,
    const int* __restrict__ labels, float* __restrict__ mid) {
    int bid = blockIdx.x, b = bid >> 1, dir = bid & 1, lane = threadIdx.x;
    const int* y = labels + b * Ln;
    int y0 = y[2 * lane], y1 = y[2 * lane + 1];
    int ym1 = lane ? y[2 * lane - 1] : -1;
    int yp2 = (lane < 63) ? y[2 * lane + 2] : -1;
    double sk1 = (lane > 0 && y0 != ym1) ? 1. : 0.;   // fwd skip into s=4l+1
    double sk3 = (y1 != y0) ? 1. : 0.;                // fwd skip into s=4l+3
    double sB1 = (y0 != y1) ? 1. : 0.;                // bwd skip from s=4l+1
    double sB3 = (lane < 63 && yp2 != y1) ? 1. : 0.;  // bwd skip from s=4l+3
    const _Float16* plB = plab + (size_t)b * Tn * Ln + 2 * lane;
    const _Float16* pbB = pblank + b * Tn;
    double i0 = (double)(float)pbB[0];
    double i1 = (double)(float)plB[0]; // only lane0's value (j=0) is used
    float* row = mid + (size_t)bid * MS;
    if (dir == 0) scan_core<0, 512>(plB, pbB, sk1, sk3, sB1, sB3, i0, i1, lane, row);
    else          scan_core<1, 511>(plB, pbB, sk1, sk3, sB1, sB3, i0, i1, lane, row);
}

// ---------------- Kernel C: combine at the meet point, mean-reduce -----------
__global__ __launch_bounds__(64) void ctc_final2(
    const float* __restrict__ mid, float* __restrict__ out) {
    int b = blockIdx.x, lane = threadIdx.x;
    const float* ra = mid + (size_t)(2 * b) * MS;
    const float* rb = ra + MS;
    float4 va = *(const float4*)(ra + 4 * lane);
    float4 vb = *(const float4*)(rb + 4 * lane);
    float v0 = va.x + vb.x, v1 = va.y + vb.y, v2 = va.z + vb.z, v3 = va.w + vb.w;
    float v4 = (lane == 0) ? (ra[256] + rb[256]) : NEGF;
    float m = fmaxf(fmaxf(fmaxf(v0, v1), fmaxf(v2, v3)), v4);
#pragma unroll
    for (int o = 1; o < 64; o <<= 1) m = fmaxf(m, __shfl_xor(m, o, 64));
    float s = __expf(v0 - m) + __expf(v1 - m) + __expf(v2 - m) + __expf(v3 - m) + __expf(v4 - m);
#pragma unroll
    for (int o = 1; o < 64; o <<= 1) s += __shfl_xor(s, o, 64);
    if (lane == 0) {
        float ll = m + __logf(s);
        atomicAdd(out, -ll * (1.0f / Bn));
    }
}

// ---------------- Fallback (ws too small): fully fused, one block per batch --
__global__ __launch_bounds__(320) void ctc_fused(
    const float* __restrict__ logits, const int* __restrict__ labels,
    float* __restrict__ out) {
    int b = blockIdx.x, tid = threadIdx.x;
    __shared__ float row[Vn];
    __shared__ float red[12];
    __shared__ float buf[2][Sn + 4];
    bool active = tid < Sn;
    int s = active ? tid : 0;
    bool odd = (s & 1) != 0;
    int j = (s - 1) >> 1;
    const int* y = labels + b * Ln;
    int ext = odd ? y[j] : BLANKC;
    bool skipF = odd && (j > 0) && (y[j] != y[j - 1]);
    if (tid < 2) {
        buf[0][tid] = NEGF; buf[1][tid] = NEGF;
        buf[0][Sn + 2 + tid] = NEGF; buf[1][Sn + 2 + tid] = NEGF;
    }
    const float* lg = logits + (size_t)b * Tn * Vn;
    float a = NEGF;
    int cur = 0;
    int w = tid >> 6, lane = tid & 63;
    for (int t = 0; t < Tn; ++t) {
        float x = (tid < Vn) ? lg[(size_t)t * Vn + tid] : -3.0e38f;
        if (tid < Vn) row[tid] = x;
        float mx = x;
#pragma unroll
        for (int o = 32; o; o >>= 1) mx = fmaxf(mx, __shfl_xor(mx, o, 64));
        if (lane == 0) red[w] = mx;
        __syncthreads();
        mx = fmaxf(fmaxf(fmaxf(red[0], red[1]), fmaxf(red[2], red[3])), red[4]);
        float e = (tid < Vn) ? __expf(x - mx) : 0.f;
        float sm = e;
#pragma unroll
        for (int o = 32; o; o >>= 1) sm += __shfl_xor(sm, o, 64);
        if (lane == 0) red[5 + w] = sm;
        __syncthreads();
        float lse = mx + __logf(red[5] + red[6] + red[7] + red[8] + red[9]);
        float lpv = row[ext] - lse;
        if (t == 0) {
            a = (s <= 1) ? lpv : NEGF;
        } else {
            if (active) buf[cur][2 + s] = a;
            __syncthreads();
            float a2 = buf[cur][2 + s - 1];
            float a3 = skipF ? buf[cur][2 + s - 2] : NEGF;
            a = lse3f(a, a2, a3) + lpv;
            cur ^= 1;
        }
        __syncthreads();
    }
    if (s == Sn - 1) red[10] = a;
    if (s == Sn - 2) red[11] = a;
    __syncthreads();
    if (tid == 0) {
        float m = fmaxf(red[10], red[11]);
        float ll = m + __logf(__expf(red[10] - m) + __expf(red[11] - m));
        atomicAdd(out, -ll * (1.0f / Bn));
    }
}

extern "C" void kernel_launch(void* const* d_in, const int* in_sizes, int n_in,
                              void* d_out, int out_size, void* d_ws, size_t ws_size,
                              hipStream_t stream) {
    const int*   y_true = (const int*)d_in[0];
    const float* y_pred = (const float*)d_in[1];
    float* out = (float*)d_out;

    hipMemsetAsync(out, 0, sizeof(float), stream);

    char* ws = (char*)d_ws;
    size_t midB = (size_t)256 * MS * sizeof(float);        // 266240
    size_t pblB = (size_t)Bn * Tn * sizeof(_Float16);      // 262144
    size_t plabB = (size_t)Bn * Tn * Ln * sizeof(_Float16); // 33.55 MB
    if (ws_size >= midB + pblB + plabB) {
        float*     mid    = (float*)ws;
        _Float16*  pblank = (_Float16*)(ws + midB);
        _Float16*  plab   = (_Float16*)(ws + midB + pblB);
        ctc_prep<<<dim3(16, Bn), 256, 0, stream>>>(y_pred, y_true, plab, pblank);
        ctc_scan2<<<dim3(256), 64, 0, stream>>>(plab, pblank, y_true, mid);
        ctc_final2<<<dim3(Bn), 64, 0, stream>>>(mid, out);
    } else {
        ctc_fused<<<dim3(Bn), 320, 0, stream>>>(y_pred, y_true, out);
    }
}